// Round 2
// baseline (419.713 us; speedup 1.0000x reference)
//
#include <hip/hip_runtime.h>
#include <stdint.h>

#define E_TOTAL 1000000
#define N_NODES 100000
#define FD      128
#define ETILE   64
#define NTILES  (E_TOTAL / ETILE)   // 15625 exactly
#define GRID    3125                // 5 tiles per block exactly

typedef __attribute__((ext_vector_type(8))) short short8;
typedef __attribute__((ext_vector_type(4))) short short4v;
typedef __attribute__((ext_vector_type(4))) float f32x4;

// round-to-nearest-even fp32 -> bf16 (bit pattern in a short)
__device__ __forceinline__ short f2bf(float f) {
  union { float f; unsigned u; } v; v.f = f;
  unsigned r = (v.u + 0x7FFFu + ((v.u >> 16) & 1u)) >> 16;
  return (short)(r & 0xFFFFu);
}

// ---- pre-pass: x fp32 -> bf16 table in workspace (8 floats / thread) ----
__global__ __launch_bounds__(256)
void convert_x_kernel(const float* __restrict__ x, short* __restrict__ xb) {
  const int i = (blockIdx.x * 256 + threadIdx.x) * 8;   // grid sized exactly
  float4 a = *(const float4*)(x + i);
  float4 b = *(const float4*)(x + i + 4);
  short8 s;
  s[0] = f2bf(a.x); s[1] = f2bf(a.y); s[2] = f2bf(a.z); s[3] = f2bf(a.w);
  s[4] = f2bf(b.x); s[5] = f2bf(b.y); s[6] = f2bf(b.z); s[7] = f2bf(b.w);
  *(short8*)(xb + i) = s;
}

template <bool USEBF>
__global__ __launch_bounds__(256, 4)
void linkpred_kernel(const float* __restrict__ x,
                     const short* __restrict__ xbf,    // bf16 x table (if USEBF)
                     const int* __restrict__ ei,       // [2][E_TOTAL], int32
                     const float* __restrict__ W1, const float* __restrict__ b1,
                     const float* __restrict__ A1,
                     const float* __restrict__ W2, const float* __restrict__ b2,
                     const float* __restrict__ A2,
                     const float* __restrict__ W3, const float* __restrict__ b3,
                     const float* __restrict__ A3,
                     const float* __restrict__ Wf, const float* __restrict__ bfp,
                     float* __restrict__ out)
{
  // One overlaid region R (33792 B):
  //   phase A/B: H0[64][264] bf16  (gather + layer1 A-reads)
  //   phase C/D: H1[64][72] bf16 @ +0,  H2[64][40] bf16 @ +16384
  // H1/H2 alias H0 -> one extra barrier after layer-1 A-reads.
  __shared__ __align__(16) char R[ETILE * 264 * 2];
  __shared__ int SIDX[2][ETILE];

  short (*H0)[264] = (short(*)[264])R;
  short (*H1)[72]  = (short(*)[72])R;
  short (*H2)[40]  = (short(*)[40])(R + 16384);

  const int tid  = threadIdx.x;
  const int w    = tid >> 6;     // wave 0..3
  const int lane = tid & 63;
  const int col  = lane & 15;
  const int quad = lane >> 4;    // 0..3

  // ---------------- register-resident weight B-fragments ----------------
  // Layer1: Wcat1 = [W1 | A1] (K=256, N=128). Wave w owns cols {16w..} and {64+16w..}.
  short8 B1f[2][8];
  for (int p = 0; p < 2; ++p) {
    const int n = 16 * (w + 4 * p) + col;                     // 0..127
    const float* src = (p == 0) ? (W1 + n) : (A1 + (n - 64));
    for (int kt = 0; kt < 8; ++kt) {
      short8 f;
      for (int j = 0; j < 8; ++j)
        f[j] = f2bf(src[(kt * 32 + quad * 8 + j) * 64]);
      B1f[p][kt] = f;
    }
  }
  // Layer2: Wcat2 = [W2 | A2] (K=64, N=64). Wave w owns col pair {16*(w&1), 32+16*(w&1)}.
  short8 B2f[2][2];
  for (int p = 0; p < 2; ++p) {
    const int n = 16 * ((w & 1) + 2 * p) + col;               // 0..63
    const float* src = (p == 0) ? (W2 + n) : (A2 + (n - 32));
    for (int kt = 0; kt < 2; ++kt) {
      short8 f;
      for (int j = 0; j < 8; ++j)
        f[j] = f2bf(src[(kt * 32 + quad * 8 + j) * 32]);
      B2f[p][kt] = f;
    }
  }
  // Layer3: Wcat3 = [W3 | A3] (K=32, N=32). All waves own col pair {0,16}.
  short8 B3f[2];
  for (int p = 0; p < 2; ++p) {
    const int n = 16 * p + col;                               // 0..31
    const float* src = (p == 0) ? (W3 + n) : (A3 + (n - 16));
    short8 f;
    for (int j = 0; j < 8; ++j)
      f[j] = f2bf(src[(quad * 8 + j) * 16]);
    B3f[p] = f;
  }
  const float b1v = b1[16 * w + col];
  const float b2v = b2[16 * (w & 1) + col];
  const float b3v = b3[col];
  const float bfv = bfp[0];
  const float wfv = Wf[col];
  const f32x4 zero = {0.f, 0.f, 0.f, 0.f};

  for (int tile = blockIdx.x; tile < NTILES; tile += GRID) {
    const int e0 = tile * ETILE;

    // ---- stage edge indices ----
    if (tid < ETILE)            SIDX[0][tid] = ei[e0 + tid];
    else if (tid < 2 * ETILE)   SIDX[1][tid - ETILE] = ei[E_TOTAL + e0 + (tid - ETILE)];
    __syncthreads();

    // ---- gather into H0 (concat [x[src] | x[dst]] as bf16) ----
    if (USEBF) {
      // 128 node-row slots; 16 slots (16-lane groups) per wave-iteration.
      for (int it = 0; it < 8; ++it) {
        const int ns   = it * 16 + w * 4 + (lane >> 4);  // 0..127
        const int e    = ns >> 1, half = ns & 1;
        const int node = SIDX[half][e];
        short8 v = *(const short8*)(xbf + (size_t)node * FD + col * 8);
        *(short8*)&H0[e][half * FD + col * 8] = v;
      }
    } else {
      for (int it = 0; it < ETILE / 4; ++it) {
        const int e    = it * 4 + w;
        const int node = SIDX[lane >> 5][e];
        const int cc   = lane & 31;
        float4 v = ((const float4*)(x + (size_t)node * FD))[cc];
        short4v s;
        s[0] = f2bf(v.x); s[1] = f2bf(v.y); s[2] = f2bf(v.z); s[3] = f2bf(v.w);
        *(short4v*)&H0[e][lane * 4] = s;
      }
    }
    __syncthreads();

    // ---- layer 1: [64x256] @ [256x128], wave w -> all M, cols {16w, 64+16w} ----
    f32x4 acc[4][2];
    for (int mt = 0; mt < 4; ++mt) { acc[mt][0] = zero; acc[mt][1] = zero; }
    for (int kt = 0; kt < 8; ++kt) {
      for (int mt = 0; mt < 4; ++mt) {
        short8 a = *(const short8*)&H0[mt * 16 + col][kt * 32 + quad * 8];
        acc[mt][0] = __builtin_amdgcn_mfma_f32_16x16x32_bf16(a, B1f[0][kt], acc[mt][0], 0, 0, 0);
        acc[mt][1] = __builtin_amdgcn_mfma_f32_16x16x32_bf16(a, B1f[1][kt], acc[mt][1], 0, 0, 0);
      }
    }
    __syncthreads();   // H1 aliases H0: all A-reads must retire first

    for (int mt = 0; mt < 4; ++mt)
      for (int r = 0; r < 4; ++r) {
        float o = fmaxf(acc[mt][0][r] + b1v, 0.f);        // relu(h@W1 + b1)
        float h = fmaxf(o + acc[mt][1][r], 0.f);          // relu(out + h@A1)
        H1[mt * 16 + quad * 4 + r][16 * w + col] = f2bf(h);
      }
    __syncthreads();

    // ---- layer 2: [64x64] @ [64x64], waves split M in halves ----
    f32x4 acc2[2][2];
    acc2[0][0] = zero; acc2[0][1] = zero; acc2[1][0] = zero; acc2[1][1] = zero;
    for (int kt = 0; kt < 2; ++kt)
      for (int mi = 0; mi < 2; ++mi) {
        const int m = (2 * (w >> 1) + mi) * 16 + col;
        short8 a = *(const short8*)&H1[m][kt * 32 + quad * 8];
        acc2[mi][0] = __builtin_amdgcn_mfma_f32_16x16x32_bf16(a, B2f[0][kt], acc2[mi][0], 0, 0, 0);
        acc2[mi][1] = __builtin_amdgcn_mfma_f32_16x16x32_bf16(a, B2f[1][kt], acc2[mi][1], 0, 0, 0);
      }
    for (int mi = 0; mi < 2; ++mi)
      for (int r = 0; r < 4; ++r) {
        float o = fmaxf(acc2[mi][0][r] + b2v, 0.f);
        float h = fmaxf(o + acc2[mi][1][r], 0.f);
        H2[(2 * (w >> 1) + mi) * 16 + quad * 4 + r][16 * (w & 1) + col] = f2bf(h);
      }
    __syncthreads();

    // ---- layer 3: [64x32] @ [32x32], wave w -> M-tile w ----
    f32x4 acc3[2];
    acc3[0] = zero; acc3[1] = zero;
    {
      short8 a = *(const short8*)&H2[w * 16 + col][quad * 8];
      acc3[0] = __builtin_amdgcn_mfma_f32_16x16x32_bf16(a, B3f[0], acc3[0], 0, 0, 0);
      acc3[1] = __builtin_amdgcn_mfma_f32_16x16x32_bf16(a, B3f[1], acc3[1], 0, 0, 0);
    }

    // ---- final 16-dot via shuffle butterfly + sigmoid, packed float4 store ----
    float4 res;
    float* resp = (float*)&res;
    for (int r = 0; r < 4; ++r) {
      float o = fmaxf(acc3[0][r] + b3v, 0.f);
      float h = fmaxf(o + acc3[1][r], 0.f);
      float s = h * wfv;
      s += __shfl_xor(s, 1, 16);
      s += __shfl_xor(s, 2, 16);
      s += __shfl_xor(s, 4, 16);
      s += __shfl_xor(s, 8, 16);
      resp[r] = 1.0f / (1.0f + __expf(-(s + bfv)));
    }
    if (col == 0)
      *(float4*)(out + e0 + w * 16 + quad * 4) = res;

    __syncthreads();   // next tile's gather rewrites R (aliases H2 reads)
  }
}

extern "C" void kernel_launch(void* const* d_in, const int* in_sizes, int n_in,
                              void* d_out, int out_size, void* d_ws, size_t ws_size,
                              hipStream_t stream) {
  const float* x   = (const float*)d_in[0];
  const int*   ei  = (const int*)d_in[1];
  const float* W1  = (const float*)d_in[2];
  const float* b1  = (const float*)d_in[3];
  const float* A1  = (const float*)d_in[4];
  const float* W2  = (const float*)d_in[5];
  const float* b2  = (const float*)d_in[6];
  const float* A2  = (const float*)d_in[7];
  const float* W3  = (const float*)d_in[8];
  const float* b3  = (const float*)d_in[9];
  const float* A3  = (const float*)d_in[10];
  const float* Wf  = (const float*)d_in[11];
  const float* bfp = (const float*)d_in[12];

  const size_t xb_bytes = (size_t)N_NODES * FD * sizeof(short);  // 25.6 MB

  if (ws_size >= xb_bytes) {
    short* xb = (short*)d_ws;
    hipLaunchKernelGGL(convert_x_kernel, dim3(N_NODES * FD / (256 * 8)), dim3(256), 0, stream,
                       x, xb);
    hipLaunchKernelGGL((linkpred_kernel<true>), dim3(GRID), dim3(256), 0, stream,
                       x, (const short*)xb, ei, W1, b1, A1, W2, b2, A2, W3, b3, A3, Wf, bfp,
                       (float*)d_out);
  } else {
    hipLaunchKernelGGL((linkpred_kernel<false>), dim3(GRID), dim3(256), 0, stream,
                       x, (const short*)nullptr, ei, W1, b1, A1, W2, b2, A2, W3, b3, A3, Wf, bfp,
                       (float*)d_out);
  }
}

// Round 3
// 318.849 us; speedup vs baseline: 1.3163x; 1.3163x over previous
//
#include <hip/hip_runtime.h>
#include <stdint.h>

#define E_TOTAL 1000000
#define N_NODES 100000
#define FD      128
#define ETILE   64
#define NTILES  (E_TOTAL / ETILE)   // 15625 exactly
#define GRID    3125                // 5 tiles per block exactly

typedef __attribute__((ext_vector_type(8))) short short8;
typedef __attribute__((ext_vector_type(4))) short short4v;
typedef __attribute__((ext_vector_type(4))) float f32x4;

// round-to-nearest-even fp32 -> bf16 (bit pattern in a short)
__device__ __forceinline__ short f2bf(float f) {
  union { float f; unsigned u; } v; v.f = f;
  unsigned r = (v.u + 0x7FFFu + ((v.u >> 16) & 1u)) >> 16;
  return (short)(r & 0xFFFFu);
}

// ---- pre-pass: x fp32 -> bf16 table in workspace (8 floats / thread) ----
__global__ __launch_bounds__(256)
void convert_x_kernel(const float* __restrict__ x, short* __restrict__ xb) {
  const int i = (blockIdx.x * 256 + threadIdx.x) * 8;   // grid sized exactly
  float4 a = *(const float4*)(x + i);
  float4 b = *(const float4*)(x + i + 4);
  short8 s;
  s[0] = f2bf(a.x); s[1] = f2bf(a.y); s[2] = f2bf(a.z); s[3] = f2bf(a.w);
  s[4] = f2bf(b.x); s[5] = f2bf(b.y); s[6] = f2bf(b.z); s[7] = f2bf(b.w);
  *(short8*)(xb + i) = s;
}

template <bool USEBF>
__global__ __launch_bounds__(256, 2)   // (256,2): proven no-spill codegen (VGPR~100).
                                       // (256,4) forced a 64-VGPR budget -> weight
                                       // fragments spilled to scratch -> 2x slowdown.
void linkpred_kernel(const float* __restrict__ x,
                     const short* __restrict__ xbf,    // bf16 x table (if USEBF)
                     const int* __restrict__ ei,       // [2][E_TOTAL], int32
                     const float* __restrict__ W1, const float* __restrict__ b1,
                     const float* __restrict__ A1,
                     const float* __restrict__ W2, const float* __restrict__ b2,
                     const float* __restrict__ A2,
                     const float* __restrict__ W3, const float* __restrict__ b3,
                     const float* __restrict__ A3,
                     const float* __restrict__ Wf, const float* __restrict__ bfp,
                     float* __restrict__ out)
{
  // One overlaid region R (33792 B):
  //   phase A/B: H0[64][264] bf16  (gather + layer1 A-reads)
  //   phase C/D: H1[64][72] bf16 @ +0,  H2[64][40] bf16 @ +16384
  // H1/H2 alias H0 -> one extra barrier after layer-1 A-reads.
  __shared__ __align__(16) char R[ETILE * 264 * 2];
  __shared__ int SIDX[2][ETILE];

  short (*H0)[264] = (short(*)[264])R;
  short (*H1)[72]  = (short(*)[72])R;
  short (*H2)[40]  = (short(*)[40])(R + 16384);

  const int tid  = threadIdx.x;
  const int w    = tid >> 6;     // wave 0..3
  const int lane = tid & 63;
  const int col  = lane & 15;
  const int quad = lane >> 4;    // 0..3

  // ---------------- register-resident weight B-fragments ----------------
  // Layer1: Wcat1 = [W1 | A1] (K=256, N=128). Wave w owns cols {16w..} and {64+16w..}.
  short8 B1f[2][8];
  for (int p = 0; p < 2; ++p) {
    const int n = 16 * (w + 4 * p) + col;                     // 0..127
    const float* src = (p == 0) ? (W1 + n) : (A1 + (n - 64));
    for (int kt = 0; kt < 8; ++kt) {
      short8 f;
      for (int j = 0; j < 8; ++j)
        f[j] = f2bf(src[(kt * 32 + quad * 8 + j) * 64]);
      B1f[p][kt] = f;
    }
  }
  // Layer2: Wcat2 = [W2 | A2] (K=64, N=64). Wave w owns col pair {16*(w&1), 32+16*(w&1)}.
  short8 B2f[2][2];
  for (int p = 0; p < 2; ++p) {
    const int n = 16 * ((w & 1) + 2 * p) + col;               // 0..63
    const float* src = (p == 0) ? (W2 + n) : (A2 + (n - 32));
    for (int kt = 0; kt < 2; ++kt) {
      short8 f;
      for (int j = 0; j < 8; ++j)
        f[j] = f2bf(src[(kt * 32 + quad * 8 + j) * 32]);
      B2f[p][kt] = f;
    }
  }
  // Layer3: Wcat3 = [W3 | A3] (K=32, N=32). All waves own col pair {0,16}.
  short8 B3f[2];
  for (int p = 0; p < 2; ++p) {
    const int n = 16 * p + col;                               // 0..31
    const float* src = (p == 0) ? (W3 + n) : (A3 + (n - 16));
    short8 f;
    for (int j = 0; j < 8; ++j)
      f[j] = f2bf(src[(quad * 8 + j) * 16]);
    B3f[p] = f;
  }
  const float b1v = b1[16 * w + col];
  const float b2v = b2[16 * (w & 1) + col];
  const float b3v = b3[col];
  const float bfv = bfp[0];
  const float wfv = Wf[col];
  const f32x4 zero = {0.f, 0.f, 0.f, 0.f};

  for (int tile = blockIdx.x; tile < NTILES; tile += GRID) {
    const int e0 = tile * ETILE;

    // ---- stage edge indices ----
    if (tid < ETILE)            SIDX[0][tid] = ei[e0 + tid];
    else if (tid < 2 * ETILE)   SIDX[1][tid - ETILE] = ei[E_TOTAL + e0 + (tid - ETILE)];
    __syncthreads();

    // ---- gather into H0 (concat [x[src] | x[dst]] as bf16) ----
    if (USEBF) {
      // 128 node-row slots; 16 slots (16-lane groups) per wave-iteration.
      for (int it = 0; it < 8; ++it) {
        const int ns   = it * 16 + w * 4 + (lane >> 4);  // 0..127
        const int e    = ns >> 1, half = ns & 1;
        const int node = SIDX[half][e];
        short8 v = *(const short8*)(xbf + (size_t)node * FD + col * 8);
        *(short8*)&H0[e][half * FD + col * 8] = v;
      }
    } else {
      for (int it = 0; it < ETILE / 4; ++it) {
        const int e    = it * 4 + w;
        const int node = SIDX[lane >> 5][e];
        const int cc   = lane & 31;
        float4 v = ((const float4*)(x + (size_t)node * FD))[cc];
        short4v s;
        s[0] = f2bf(v.x); s[1] = f2bf(v.y); s[2] = f2bf(v.z); s[3] = f2bf(v.w);
        *(short4v*)&H0[e][lane * 4] = s;
      }
    }
    __syncthreads();

    // ---- layer 1: [64x256] @ [256x128], wave w -> all M, cols {16w, 64+16w} ----
    f32x4 acc[4][2];
    for (int mt = 0; mt < 4; ++mt) { acc[mt][0] = zero; acc[mt][1] = zero; }
    for (int kt = 0; kt < 8; ++kt) {
      for (int mt = 0; mt < 4; ++mt) {
        short8 a = *(const short8*)&H0[mt * 16 + col][kt * 32 + quad * 8];
        acc[mt][0] = __builtin_amdgcn_mfma_f32_16x16x32_bf16(a, B1f[0][kt], acc[mt][0], 0, 0, 0);
        acc[mt][1] = __builtin_amdgcn_mfma_f32_16x16x32_bf16(a, B1f[1][kt], acc[mt][1], 0, 0, 0);
      }
    }
    __syncthreads();   // H1 aliases H0: all A-reads must retire first

    for (int mt = 0; mt < 4; ++mt)
      for (int r = 0; r < 4; ++r) {
        float o = fmaxf(acc[mt][0][r] + b1v, 0.f);        // relu(h@W1 + b1)
        float h = fmaxf(o + acc[mt][1][r], 0.f);          // relu(out + h@A1)
        H1[mt * 16 + quad * 4 + r][16 * w + col] = f2bf(h);
      }
    __syncthreads();

    // ---- layer 2: [64x64] @ [64x64], waves split M in halves ----
    f32x4 acc2[2][2];
    acc2[0][0] = zero; acc2[0][1] = zero; acc2[1][0] = zero; acc2[1][1] = zero;
    for (int kt = 0; kt < 2; ++kt)
      for (int mi = 0; mi < 2; ++mi) {
        const int m = (2 * (w >> 1) + mi) * 16 + col;
        short8 a = *(const short8*)&H1[m][kt * 32 + quad * 8];
        acc2[mi][0] = __builtin_amdgcn_mfma_f32_16x16x32_bf16(a, B2f[0][kt], acc2[mi][0], 0, 0, 0);
        acc2[mi][1] = __builtin_amdgcn_mfma_f32_16x16x32_bf16(a, B2f[1][kt], acc2[mi][1], 0, 0, 0);
      }
    for (int mi = 0; mi < 2; ++mi)
      for (int r = 0; r < 4; ++r) {
        float o = fmaxf(acc2[mi][0][r] + b2v, 0.f);
        float h = fmaxf(o + acc2[mi][1][r], 0.f);
        H2[(2 * (w >> 1) + mi) * 16 + quad * 4 + r][16 * (w & 1) + col] = f2bf(h);
      }
    __syncthreads();

    // ---- layer 3: [64x32] @ [32x32], wave w -> M-tile w ----
    f32x4 acc3[2];
    acc3[0] = zero; acc3[1] = zero;
    {
      short8 a = *(const short8*)&H2[w * 16 + col][quad * 8];
      acc3[0] = __builtin_amdgcn_mfma_f32_16x16x32_bf16(a, B3f[0], acc3[0], 0, 0, 0);
      acc3[1] = __builtin_amdgcn_mfma_f32_16x16x32_bf16(a, B3f[1], acc3[1], 0, 0, 0);
    }

    // ---- final 16-dot via shuffle butterfly + sigmoid, packed float4 store ----
    float4 res;
    float* resp = (float*)&res;
    for (int r = 0; r < 4; ++r) {
      float o = fmaxf(acc3[0][r] + b3v, 0.f);
      float h = fmaxf(o + acc3[1][r], 0.f);
      float s = h * wfv;
      s += __shfl_xor(s, 1, 16);
      s += __shfl_xor(s, 2, 16);
      s += __shfl_xor(s, 4, 16);
      s += __shfl_xor(s, 8, 16);
      resp[r] = 1.0f / (1.0f + __expf(-(s + bfv)));
    }
    if (col == 0)
      *(float4*)(out + e0 + w * 16 + quad * 4) = res;

    __syncthreads();   // next tile's gather rewrites R (aliases H2 reads)
  }
}

extern "C" void kernel_launch(void* const* d_in, const int* in_sizes, int n_in,
                              void* d_out, int out_size, void* d_ws, size_t ws_size,
                              hipStream_t stream) {
  const float* x   = (const float*)d_in[0];
  const int*   ei  = (const int*)d_in[1];
  const float* W1  = (const float*)d_in[2];
  const float* b1  = (const float*)d_in[3];
  const float* A1  = (const float*)d_in[4];
  const float* W2  = (const float*)d_in[5];
  const float* b2  = (const float*)d_in[6];
  const float* A2  = (const float*)d_in[7];
  const float* W3  = (const float*)d_in[8];
  const float* b3  = (const float*)d_in[9];
  const float* A3  = (const float*)d_in[10];
  const float* Wf  = (const float*)d_in[11];
  const float* bfp = (const float*)d_in[12];

  const size_t xb_bytes = (size_t)N_NODES * FD * sizeof(short);  // 25.6 MB

  if (ws_size >= xb_bytes) {
    short* xb = (short*)d_ws;
    hipLaunchKernelGGL(convert_x_kernel, dim3(N_NODES * FD / (256 * 8)), dim3(256), 0, stream,
                       x, xb);
    hipLaunchKernelGGL((linkpred_kernel<true>), dim3(GRID), dim3(256), 0, stream,
                       x, (const short*)xb, ei, W1, b1, A1, W2, b2, A2, W3, b3, A3, Wf, bfp,
                       (float*)d_out);
  } else {
    hipLaunchKernelGGL((linkpred_kernel<false>), dim3(GRID), dim3(256), 0, stream,
                       x, (const short*)nullptr, ei, W1, b1, A1, W2, b2, A2, W3, b3, A3, Wf, bfp,
                       (float*)d_out);
  }
}

// Round 4
// 246.733 us; speedup vs baseline: 1.7011x; 1.2923x over previous
//
#include <hip/hip_runtime.h>
#include <stdint.h>

#define E_TOTAL 1000000
#define N_NODES 100000
#define FD      128
#define ETILE   64
#define NTILES  (E_TOTAL / ETILE)   // 15625 exactly
#define GRID    3125                // 5 tiles per block exactly
#define KTILES  5

typedef __attribute__((ext_vector_type(8))) short short8;
typedef __attribute__((ext_vector_type(4))) short short4v;
typedef __attribute__((ext_vector_type(4))) float f32x4;

// round-to-nearest-even fp32 -> bf16 (bit pattern in a short)
__device__ __forceinline__ short f2bf(float f) {
  union { float f; unsigned u; } v; v.f = f;
  unsigned r = (v.u + 0x7FFFu + ((v.u >> 16) & 1u)) >> 16;
  return (short)(r & 0xFFFFu);
}

// ---- pre-pass: x fp32 -> bf16 table in workspace (8 floats / thread) ----
__global__ __launch_bounds__(256)
void convert_x_kernel(const float* __restrict__ x, short* __restrict__ xb) {
  const int i = (blockIdx.x * 256 + threadIdx.x) * 8;   // grid sized exactly
  float4 a = *(const float4*)(x + i);
  float4 b = *(const float4*)(x + i + 4);
  short8 s;
  s[0] = f2bf(a.x); s[1] = f2bf(a.y); s[2] = f2bf(a.z); s[3] = f2bf(a.w);
  s[4] = f2bf(b.x); s[5] = f2bf(b.y); s[6] = f2bf(b.z); s[7] = f2bf(b.w);
  *(short8*)(xb + i) = s;
}

template <bool USEBF>
__global__ __launch_bounds__(256, 2)   // (256,2): proven no-spill codegen.
                                       // (256,4) forced a 64-VGPR budget -> weight
                                       // fragments spilled to scratch -> 2x slowdown.
void linkpred_kernel(const float* __restrict__ x,
                     const short* __restrict__ xbf,    // bf16 x table (if USEBF)
                     const int* __restrict__ ei,       // [2][E_TOTAL], int32
                     const float* __restrict__ W1, const float* __restrict__ b1,
                     const float* __restrict__ A1,
                     const float* __restrict__ W2, const float* __restrict__ b2,
                     const float* __restrict__ A2,
                     const float* __restrict__ W3, const float* __restrict__ b3,
                     const float* __restrict__ A3,
                     const float* __restrict__ Wf, const float* __restrict__ bfp,
                     float* __restrict__ out)
{
  // One overlaid region R (33792 B):
  //   phase A/B: H0[64][264] bf16  (gather + layer1 A-reads)
  //   phase C/D: H1[64][72] bf16 @ +0,  H2[64][40] bf16 @ +16384
  // H1/H2 alias H0 -> one extra barrier after layer-1 A-reads.
  __shared__ __align__(16) char R[ETILE * 264 * 2];
  __shared__ int SIDX[2][ETILE];

  short (*H0)[264] = (short(*)[264])R;
  short (*H1)[72]  = (short(*)[72])R;
  short (*H2)[40]  = (short(*)[40])(R + 16384);

  const int tid  = threadIdx.x;
  const int w    = tid >> 6;     // wave 0..3
  const int lane = tid & 63;
  const int col  = lane & 15;
  const int quad = lane >> 4;    // 0..3

  // ---------------- register-resident weight B-fragments ----------------
  // Layer1: Wcat1 = [W1 | A1] (K=256, N=128). Wave w owns cols {16w..} and {64+16w..}.
  short8 B1f[2][8];
  for (int p = 0; p < 2; ++p) {
    const int n = 16 * (w + 4 * p) + col;                     // 0..127
    const float* src = (p == 0) ? (W1 + n) : (A1 + (n - 64));
    for (int kt = 0; kt < 8; ++kt) {
      short8 f;
      for (int j = 0; j < 8; ++j)
        f[j] = f2bf(src[(kt * 32 + quad * 8 + j) * 64]);
      B1f[p][kt] = f;
    }
  }
  // Layer2: Wcat2 = [W2 | A2] (K=64, N=64). Wave w owns col pair {16*(w&1), 32+16*(w&1)}.
  short8 B2f[2][2];
  for (int p = 0; p < 2; ++p) {
    const int n = 16 * ((w & 1) + 2 * p) + col;               // 0..63
    const float* src = (p == 0) ? (W2 + n) : (A2 + (n - 32));
    for (int kt = 0; kt < 2; ++kt) {
      short8 f;
      for (int j = 0; j < 8; ++j)
        f[j] = f2bf(src[(kt * 32 + quad * 8 + j) * 32]);
      B2f[p][kt] = f;
    }
  }
  // Layer3: Wcat3 = [W3 | A3] (K=32, N=32). All waves own col pair {0,16}.
  short8 B3f[2];
  for (int p = 0; p < 2; ++p) {
    const int n = 16 * p + col;                               // 0..31
    const float* src = (p == 0) ? (W3 + n) : (A3 + (n - 16));
    short8 f;
    for (int j = 0; j < 8; ++j)
      f[j] = f2bf(src[(quad * 8 + j) * 16]);
    B3f[p] = f;
  }
  const float b1v = b1[16 * w + col];
  const float b2v = b2[16 * (w & 1) + col];
  const float b3v = b3[col];
  const float bfv = bfp[0];
  const float wfv = Wf[col];
  const f32x4 zero = {0.f, 0.f, 0.f, 0.f};

  // ---- prologue: stage tile-0 edge indices ----
  {
    const int e0 = blockIdx.x * ETILE;
    if (tid < 2 * ETILE)
      SIDX[tid >> 6][tid & 63] = ei[(tid >> 6) * E_TOTAL + e0 + (tid & 63)];
  }
  __syncthreads();

  int tile = blockIdx.x;
  for (int k = 0; k < KTILES; ++k, tile += GRID) {
    const int e0 = tile * ETILE;

    // ---- prefetch next tile's edge indices (latency hidden behind this tile) ----
    int nxt = 0;
    const bool pf = (tid < 2 * ETILE) && (k < KTILES - 1);
    if (pf) nxt = ei[(tid >> 6) * E_TOTAL + (e0 + GRID * ETILE) + (tid & 63)];

    // ---- gather into H0 (concat [x[src] | x[dst]] as bf16) ----
    // 16 independent loads per thread, explicitly staged: max loads in flight.
    if (USEBF) {
      short4v g[16];
#pragma unroll
      for (int it = 0; it < 16; ++it) {
        const int e    = it * 4 + w;
        const int node = SIDX[lane >> 5][e];   // lanes 0..31: src, 32..63: dst
        g[it] = *(const short4v*)(xbf + (size_t)node * FD + (lane & 31) * 4);
      }
#pragma unroll
      for (int it = 0; it < 16; ++it) {
        const int e = it * 4 + w;
        *(short4v*)&H0[e][(lane >> 5) * FD + (lane & 31) * 4] = g[it];
      }
    } else {
      for (int it = 0; it < ETILE / 4; ++it) {
        const int e    = it * 4 + w;
        const int node = SIDX[lane >> 5][e];
        const int cc   = lane & 31;
        float4 v = ((const float4*)(x + (size_t)node * FD))[cc];
        short4v s;
        s[0] = f2bf(v.x); s[1] = f2bf(v.y); s[2] = f2bf(v.z); s[3] = f2bf(v.w);
        *(short4v*)&H0[e][lane * 4] = s;
      }
    }
    __syncthreads();

    // SIDX is dead now (all gather reads retired at the barrier): commit prefetch.
    if (pf) SIDX[tid >> 6][tid & 63] = nxt;

    // ---- layer 1: [64x256] @ [256x128], wave w -> all M, cols {16w, 64+16w} ----
    f32x4 acc[4][2];
    for (int mt = 0; mt < 4; ++mt) { acc[mt][0] = zero; acc[mt][1] = zero; }
    for (int kt = 0; kt < 8; ++kt) {
      for (int mt = 0; mt < 4; ++mt) {
        short8 a = *(const short8*)&H0[mt * 16 + col][kt * 32 + quad * 8];
        acc[mt][0] = __builtin_amdgcn_mfma_f32_16x16x32_bf16(a, B1f[0][kt], acc[mt][0], 0, 0, 0);
        acc[mt][1] = __builtin_amdgcn_mfma_f32_16x16x32_bf16(a, B1f[1][kt], acc[mt][1], 0, 0, 0);
      }
    }
    __syncthreads();   // H1 aliases H0: all A-reads must retire first

    for (int mt = 0; mt < 4; ++mt)
      for (int r = 0; r < 4; ++r) {
        float o = fmaxf(acc[mt][0][r] + b1v, 0.f);        // relu(h@W1 + b1)
        float h = fmaxf(o + acc[mt][1][r], 0.f);          // relu(out + h@A1)
        H1[mt * 16 + quad * 4 + r][16 * w + col] = f2bf(h);
      }
    __syncthreads();

    // ---- layer 2: [64x64] @ [64x64], waves split M in halves ----
    f32x4 acc2[2][2];
    acc2[0][0] = zero; acc2[0][1] = zero; acc2[1][0] = zero; acc2[1][1] = zero;
    for (int kt = 0; kt < 2; ++kt)
      for (int mi = 0; mi < 2; ++mi) {
        const int m = (2 * (w >> 1) + mi) * 16 + col;
        short8 a = *(const short8*)&H1[m][kt * 32 + quad * 8];
        acc2[mi][0] = __builtin_amdgcn_mfma_f32_16x16x32_bf16(a, B2f[0][kt], acc2[mi][0], 0, 0, 0);
        acc2[mi][1] = __builtin_amdgcn_mfma_f32_16x16x32_bf16(a, B2f[1][kt], acc2[mi][1], 0, 0, 0);
      }
    for (int mi = 0; mi < 2; ++mi)
      for (int r = 0; r < 4; ++r) {
        float o = fmaxf(acc2[mi][0][r] + b2v, 0.f);
        float h = fmaxf(o + acc2[mi][1][r], 0.f);
        H2[(2 * (w >> 1) + mi) * 16 + quad * 4 + r][16 * (w & 1) + col] = f2bf(h);
      }
    __syncthreads();

    // ---- layer 3: [64x32] @ [32x32], wave w -> M-tile w ----
    f32x4 acc3[2];
    acc3[0] = zero; acc3[1] = zero;
    {
      short8 a = *(const short8*)&H2[w * 16 + col][quad * 8];
      acc3[0] = __builtin_amdgcn_mfma_f32_16x16x32_bf16(a, B3f[0], acc3[0], 0, 0, 0);
      acc3[1] = __builtin_amdgcn_mfma_f32_16x16x32_bf16(a, B3f[1], acc3[1], 0, 0, 0);
    }

    // ---- final 16-dot via shuffle butterfly + sigmoid, packed float4 store ----
    float4 res;
    float* resp = (float*)&res;
    for (int r = 0; r < 4; ++r) {
      float o = fmaxf(acc3[0][r] + b3v, 0.f);
      float h = fmaxf(o + acc3[1][r], 0.f);
      float s = h * wfv;
      s += __shfl_xor(s, 1, 16);
      s += __shfl_xor(s, 2, 16);
      s += __shfl_xor(s, 4, 16);
      s += __shfl_xor(s, 8, 16);
      resp[r] = 1.0f / (1.0f + __expf(-(s + bfv)));
    }
    if (col == 0)
      *(float4*)(out + e0 + w * 16 + quad * 4) = res;

    __syncthreads();   // next tile's gather rewrites R (aliases H2 reads)
  }
}

extern "C" void kernel_launch(void* const* d_in, const int* in_sizes, int n_in,
                              void* d_out, int out_size, void* d_ws, size_t ws_size,
                              hipStream_t stream) {
  const float* x   = (const float*)d_in[0];
  const int*   ei  = (const int*)d_in[1];
  const float* W1  = (const float*)d_in[2];
  const float* b1  = (const float*)d_in[3];
  const float* A1  = (const float*)d_in[4];
  const float* W2  = (const float*)d_in[5];
  const float* b2  = (const float*)d_in[6];
  const float* A2  = (const float*)d_in[7];
  const float* W3  = (const float*)d_in[8];
  const float* b3  = (const float*)d_in[9];
  const float* A3  = (const float*)d_in[10];
  const float* Wf  = (const float*)d_in[11];
  const float* bfp = (const float*)d_in[12];

  const size_t xb_bytes = (size_t)N_NODES * FD * sizeof(short);  // 25.6 MB

  if (ws_size >= xb_bytes) {
    short* xb = (short*)d_ws;
    hipLaunchKernelGGL(convert_x_kernel, dim3(N_NODES * FD / (256 * 8)), dim3(256), 0, stream,
                       x, xb);
    hipLaunchKernelGGL((linkpred_kernel<true>), dim3(GRID), dim3(256), 0, stream,
                       x, (const short*)xb, ei, W1, b1, A1, W2, b2, A2, W3, b3, A3, Wf, bfp,
                       (float*)d_out);
  } else {
    hipLaunchKernelGGL((linkpred_kernel<false>), dim3(GRID), dim3(256), 0, stream,
                       x, (const short*)nullptr, ei, W1, b1, A1, W2, b2, A2, W3, b3, A3, Wf, bfp,
                       (float*)d_out);
  }
}